// Round 2
// baseline (6829.008 us; speedup 1.0000x reference)
//
#include <hip/hip_runtime.h>
#include <stdint.h>
#include <math.h>

// Replicate jax.random threefry2x32 exactly (jax_threefry_partitionable=True).
#define PARTITIONABLE 1

namespace {

constexpr int kB = 4096;
constexpr int kN = 256;
constexpr int kSweeps = 200;
constexpr int kSamp = 8;                 // samples per block
constexpr int kBlocks = kB / kSamp;      // 512
constexpr int kW = kN / 32;              // 8 spin words per sample

struct K2 { uint32_t a, b; };

__host__ __device__ constexpr uint32_t crotl(uint32_t x, int d) {
  return (x << d) | (x >> (32 - d));
}

// Threefry-2x32, 20 rounds, exactly as jax/_src/prng.py
__host__ __device__ constexpr K2 ctf(uint32_t k0, uint32_t k1, uint32_t c0, uint32_t c1) {
  uint32_t ks0 = k0, ks1 = k1, ks2 = k0 ^ k1 ^ 0x1BD11BDAu;
  uint32_t x0 = c0 + ks0, x1 = c1 + ks1;
  const int r0[4] = {13, 15, 26, 6};
  const int r1[4] = {17, 29, 16, 24};
  for (int i = 0; i < 4; ++i) { x0 += x1; x1 = crotl(x1, r0[i]); x1 ^= x0; }
  x0 += ks1; x1 += ks2 + 1u;
  for (int i = 0; i < 4; ++i) { x0 += x1; x1 = crotl(x1, r1[i]); x1 ^= x0; }
  x0 += ks2; x1 += ks0 + 2u;
  for (int i = 0; i < 4; ++i) { x0 += x1; x1 = crotl(x1, r0[i]); x1 ^= x0; }
  x0 += ks0; x1 += ks1 + 3u;
  for (int i = 0; i < 4; ++i) { x0 += x1; x1 = crotl(x1, r1[i]); x1 ^= x0; }
  x0 += ks1; x1 += ks2 + 4u;
  for (int i = 0; i < 4; ++i) { x0 += x1; x1 = crotl(x1, r0[i]); x1 ^= x0; }
  x0 += ks2; x1 += ks0 + 5u;
  return K2{x0, x1};
}

struct KeyTable {
  uint32_t s0k[2];               // key for initial spins (k0)
  uint32_t sk[kSweeps][4];       // per sweep: k1a,k1b (accept), k2a,k2b (mask)
};

constexpr KeyTable make_keys() {
  KeyTable t{};
  K2 root{0u, 42u};              // jax.random.key(42) -> (hi=0, lo=42)
#if PARTITIONABLE
  K2 k0 = ctf(root.a, root.b, 0u, 0u);
  K2 kl = ctf(root.a, root.b, 0u, 1u);
#else
  K2 p0 = ctf(root.a, root.b, 0u, 2u);
  K2 p1 = ctf(root.a, root.b, 1u, 3u);
  K2 k0{p0.a, p1.a};
  K2 kl{p0.b, p1.b};
#endif
  t.s0k[0] = k0.a; t.s0k[1] = k0.b;
  K2 k = kl;
  for (int s = 0; s < kSweeps; ++s) {
#if PARTITIONABLE
    K2 kn = ctf(k.a, k.b, 0u, 0u);
    K2 k1 = ctf(k.a, k.b, 0u, 1u);
    K2 k2 = ctf(k.a, k.b, 0u, 2u);
#else
    K2 q0 = ctf(k.a, k.b, 0u, 3u);
    K2 q1 = ctf(k.a, k.b, 1u, 4u);
    K2 q2 = ctf(k.a, k.b, 2u, 5u);
    K2 kn{q0.a, q1.a};
    K2 k1{q2.a, q0.b};
    K2 k2{q1.b, q2.b};
#endif
    t.sk[s][0] = k1.a; t.sk[s][1] = k1.b;
    t.sk[s][2] = k2.a; t.sk[s][3] = k2.b;
    k = kn;
  }
  return t;
}

__constant__ KeyTable g_keys = make_keys();

__device__ __forceinline__ uint32_t rng_bits32(uint32_t ka, uint32_t kb, uint32_t m) {
#if PARTITIONABLE
  K2 r = ctf(ka, kb, 0u, m);
  return r.a ^ r.b;
#else
  constexpr uint32_t H = (uint32_t)(kB * kN / 2);
  uint32_t p = (m < H) ? m : (m - H);
  K2 r = ctf(ka, kb, p, p + H);
  return (m < H) ? r.a : r.b;
#endif
}

__device__ __forceinline__ float bits_to_uniform(uint32_t bits) {
  // jax: bitcast(bits >> 9 | 0x3f800000) - 1.0
  return __uint_as_float((bits >> 9) | 0x3f800000u) - 1.0f;
}

__global__ void prep_kernel(const float* __restrict__ gamma,
                            float* __restrict__ jsym,
                            float* __restrict__ betas) {
  int e = blockIdx.x * blockDim.x + threadIdx.x;   // 0..65535
  int i = e / kN, j = e % kN;
  float v = 0.0f;
  if (i < j) v = gamma[i * kN + j];
  else if (i > j) v = gamma[j * kN + i];
  jsym[e] = v;
  if (e < kSweeps) {
    double l0 = log(0.1), l1 = log(5.0);
    betas[e] = (float)exp(l0 + (l1 - l0) * (double)e / (double)(kSweeps - 1));
  }
}

// Exact matvec over packed-bit spins:
//   acc[g] += sum_j (bit_j(g) ? -1 : +1) * Jrow[j], j ascending.
// fmaf(+-1.0f, J, a) rounds identically to fmaf(J, +-1.0f, a) and to a +- J,
// so this is bit-identical to the float-spin version.
// wv: lane l holds spin word l (l = g*8+q, g=sample, q=j>>5), wave-uniform
// after readlane -> the select compiles to scalar ops + v_fmac with SGPR src.
__device__ __forceinline__ void matvec_bits(const float4* __restrict__ jrow,
                                            uint32_t wv, float (&acc)[kSamp]) {
  float4 c[8], p[8];
#pragma unroll
  for (int r = 0; r < 8; ++r) c[r] = jrow[r];

#pragma unroll
  for (int q = 0; q < 8; ++q) {            // 32 j's per iteration
    if (q < 7) {
#pragma unroll
      for (int r = 0; r < 8; ++r) p[r] = jrow[(q + 1) * 8 + r];
    }
    uint32_t w[kSamp];
#pragma unroll
    for (int g = 0; g < kSamp; ++g)
      w[g] = (uint32_t)__builtin_amdgcn_readlane((int)wv, g * 8 + q);

#pragma unroll
    for (int jf = 0; jf < 8; ++jf) {       // 4 j's per float4
      const float4 cv = c[jf];
#pragma unroll
      for (int g = 0; g < kSamp; ++g) {
        float sv = ((w[g] >> (jf * 4 + 0)) & 1u) ? -1.0f : 1.0f;
        acc[g] = fmaf(sv, cv.x, acc[g]);
      }
#pragma unroll
      for (int g = 0; g < kSamp; ++g) {
        float sv = ((w[g] >> (jf * 4 + 1)) & 1u) ? -1.0f : 1.0f;
        acc[g] = fmaf(sv, cv.y, acc[g]);
      }
#pragma unroll
      for (int g = 0; g < kSamp; ++g) {
        float sv = ((w[g] >> (jf * 4 + 2)) & 1u) ? -1.0f : 1.0f;
        acc[g] = fmaf(sv, cv.z, acc[g]);
      }
#pragma unroll
      for (int g = 0; g < kSamp; ++g) {
        float sv = ((w[g] >> (jf * 4 + 3)) & 1u) ? -1.0f : 1.0f;
        acc[g] = fmaf(sv, cv.w, acc[g]);
      }
    }
    if (q < 7) {
#pragma unroll
      for (int r = 0; r < 8; ++r) c[r] = p[r];
    }
  }
}

__global__ __launch_bounds__(256) void anneal_kernel(
    const float* __restrict__ thetas, const float* __restrict__ jsym,
    const float* __restrict__ betas, float* __restrict__ out) {
  // packed spins: [buf][g*8+q], 64 words per buffer (256 B); double-buffered
  __shared__ uint32_t sh_w[2][kSamp * kW];
  __shared__ float sh_red[kSamp][4];

  const int i = threadIdx.x;           // spin index
  const int b0 = blockIdx.x * kSamp;   // first sample of this block
  const int lane = i & 63;
  const int wid = i >> 6;

  float th[kSamp], sreg[kSamp];
#pragma unroll
  for (int g = 0; g < kSamp; ++g) th[g] = thetas[(b0 + g) * kN + i];

  // s0 = where(bernoulli(k0, 0.5), 1, -1) ; bernoulli = uniform < 0.5
#pragma unroll
  for (int g = 0; g < kSamp; ++g) {
    uint32_t m = (uint32_t)((b0 + g) * kN + i);
    float u = bits_to_uniform(rng_bits32(g_keys.s0k[0], g_keys.s0k[1], m));
    sreg[g] = (u < 0.5f) ? 1.0f : -1.0f;
  }

  // pack: bit=1 <=> s=-1 ; wave wid owns words 2*wid, 2*wid+1 (bit = i&31)
#pragma unroll
  for (int g = 0; g < kSamp; ++g) {
    uint64_t bal = __ballot(sreg[g] < 0.0f);
    if (lane == 0) {
      sh_w[0][g * kW + wid * 2 + 0] = (uint32_t)bal;
      sh_w[0][g * kW + wid * 2 + 1] = (uint32_t)(bal >> 32);
    }
  }
  __syncthreads();

  // row i of Jsym; by symmetry local_i = sum_j Jsym[i][j] * s[j]
  const float4* __restrict__ jrow = (const float4*)(jsym + i * kN);
  int cur = 0;

#pragma unroll 1
  for (int t = 0; t < kSweeps; ++t) {
    const float beta = betas[t];
    const uint32_t wv = sh_w[cur][lane];   // 64 words, one per lane

    float acc[kSamp];
#pragma unroll
    for (int g = 0; g < kSamp; ++g) acc[g] = 0.0f;

    matvec_bits(jrow, wv, acc);

    const int nxt = cur ^ 1;
    const uint32_t k1a = g_keys.sk[t][0], k1b = g_keys.sk[t][1];
    const uint32_t k2a = g_keys.sk[t][2], k2b = g_keys.sk[t][3];
#pragma unroll
    for (int g = 0; g < kSamp; ++g) {
      float s = sreg[g];
      float local = th[g] + acc[g];
      float dE = -2.0f * s * local;          // exact: (-2*s) is a power of two
      float pr = expf(-beta * dE);
      uint32_t m = (uint32_t)((b0 + g) * kN + i);
      uint32_t b1 = rng_bits32(k1a, k1b, m);
      uint32_t b2 = rng_bits32(k2a, k2b, m);
      float u1 = bits_to_uniform(b1);
      // u2 < 0.5  <=>  bit31(b2) == 0  (bit-exact)
      if ((u1 < pr) && ((b2 >> 31) == 0u)) s = -s;
      sreg[g] = s;
    }

#pragma unroll
    for (int g = 0; g < kSamp; ++g) {
      uint64_t bal = __ballot(sreg[g] < 0.0f);
      if (lane == 0) {
        sh_w[nxt][g * kW + wid * 2 + 0] = (uint32_t)bal;
        sh_w[nxt][g * kW + wid * 2 + 1] = (uint32_t)(bal >> 32);
      }
    }
    __syncthreads();   // new words visible before next sweep reads
    cur = nxt;
  }

  // E_b = sum_i s_i*theta_i + 0.5 * sum_i s_i * (Jsym s)_i
  {
    const uint32_t wv = sh_w[cur][lane];
    float acc[kSamp];
#pragma unroll
    for (int g = 0; g < kSamp; ++g) acc[g] = 0.0f;
    matvec_bits(jrow, wv, acc);

#pragma unroll
    for (int g = 0; g < kSamp; ++g) {
      float v = sreg[g] * th[g] + 0.5f * (sreg[g] * acc[g]);
#pragma unroll
      for (int off = 32; off > 0; off >>= 1) v += __shfl_down(v, off);
      if (lane == 0) sh_red[g][wid] = v;
    }
    __syncthreads();
    if (threadIdx.x < kSamp) {
      int g = threadIdx.x;
      out[b0 + g] = sh_red[g][0] + sh_red[g][1] + sh_red[g][2] + sh_red[g][3];
    }
  }
}

}  // namespace

extern "C" void kernel_launch(void* const* d_in, const int* in_sizes, int n_in,
                              void* d_out, int out_size, void* d_ws, size_t ws_size,
                              hipStream_t stream) {
  const float* thetas = (const float*)d_in[0];   // [4096, 256]
  const float* gamma  = (const float*)d_in[1];   // [256, 256]
  float* jsym  = (float*)d_ws;                              // 256 KiB
  float* betas = (float*)((char*)d_ws + kN * kN * sizeof(float));

  hipLaunchKernelGGL(prep_kernel, dim3(kN), dim3(kN), 0, stream, gamma, jsym, betas);
  hipLaunchKernelGGL(anneal_kernel, dim3(kBlocks), dim3(256), 0, stream,
                     thetas, jsym, betas, (float*)d_out);
}

// Round 3
// 3391.150 us; speedup vs baseline: 2.0138x; 2.0138x over previous
//
#include <hip/hip_runtime.h>
#include <stdint.h>
#include <math.h>

// Replicate jax.random threefry2x32 exactly (jax_threefry_partitionable=True).
#define PARTITIONABLE 1

namespace {

constexpr int kB = 4096;
constexpr int kN = 256;
constexpr int kSweeps = 200;
constexpr int kSamp = 8;                 // samples per block
constexpr int kBlocks = kB / kSamp;      // 512

struct K2 { uint32_t a, b; };

__host__ __device__ constexpr uint32_t crotl(uint32_t x, int d) {
  return (x << d) | (x >> (32 - d));
}

// Threefry-2x32, 20 rounds, exactly as jax/_src/prng.py
__host__ __device__ constexpr K2 ctf(uint32_t k0, uint32_t k1, uint32_t c0, uint32_t c1) {
  uint32_t ks0 = k0, ks1 = k1, ks2 = k0 ^ k1 ^ 0x1BD11BDAu;
  uint32_t x0 = c0 + ks0, x1 = c1 + ks1;
  const int r0[4] = {13, 15, 26, 6};
  const int r1[4] = {17, 29, 16, 24};
  for (int i = 0; i < 4; ++i) { x0 += x1; x1 = crotl(x1, r0[i]); x1 ^= x0; }
  x0 += ks1; x1 += ks2 + 1u;
  for (int i = 0; i < 4; ++i) { x0 += x1; x1 = crotl(x1, r1[i]); x1 ^= x0; }
  x0 += ks2; x1 += ks0 + 2u;
  for (int i = 0; i < 4; ++i) { x0 += x1; x1 = crotl(x1, r0[i]); x1 ^= x0; }
  x0 += ks0; x1 += ks1 + 3u;
  for (int i = 0; i < 4; ++i) { x0 += x1; x1 = crotl(x1, r1[i]); x1 ^= x0; }
  x0 += ks1; x1 += ks2 + 4u;
  for (int i = 0; i < 4; ++i) { x0 += x1; x1 = crotl(x1, r0[i]); x1 ^= x0; }
  x0 += ks2; x1 += ks0 + 5u;
  return K2{x0, x1};
}

struct KeyTable {
  uint32_t s0k[2];               // key for initial spins (k0)
  uint32_t sk[kSweeps][4];       // per sweep: k1a,k1b (accept), k2a,k2b (mask)
};

constexpr KeyTable make_keys() {
  KeyTable t{};
  K2 root{0u, 42u};              // jax.random.key(42) -> (hi=0, lo=42)
#if PARTITIONABLE
  K2 k0 = ctf(root.a, root.b, 0u, 0u);
  K2 kl = ctf(root.a, root.b, 0u, 1u);
#else
  K2 p0 = ctf(root.a, root.b, 0u, 2u);
  K2 p1 = ctf(root.a, root.b, 1u, 3u);
  K2 k0{p0.a, p1.a};
  K2 kl{p0.b, p1.b};
#endif
  t.s0k[0] = k0.a; t.s0k[1] = k0.b;
  K2 k = kl;
  for (int s = 0; s < kSweeps; ++s) {
#if PARTITIONABLE
    K2 kn = ctf(k.a, k.b, 0u, 0u);
    K2 k1 = ctf(k.a, k.b, 0u, 1u);
    K2 k2 = ctf(k.a, k.b, 0u, 2u);
#else
    K2 q0 = ctf(k.a, k.b, 0u, 3u);
    K2 q1 = ctf(k.a, k.b, 1u, 4u);
    K2 q2 = ctf(k.a, k.b, 2u, 5u);
    K2 kn{q0.a, q1.a};
    K2 k1{q2.a, q0.b};
    K2 k2{q1.b, q2.b};
#endif
    t.sk[s][0] = k1.a; t.sk[s][1] = k1.b;
    t.sk[s][2] = k2.a; t.sk[s][3] = k2.b;
    k = kn;
  }
  return t;
}

__constant__ KeyTable g_keys = make_keys();

__device__ __forceinline__ uint32_t rng_bits32(uint32_t ka, uint32_t kb, uint32_t m) {
#if PARTITIONABLE
  K2 r = ctf(ka, kb, 0u, m);
  return r.a ^ r.b;
#else
  constexpr uint32_t H = (uint32_t)(kB * kN / 2);
  uint32_t p = (m < H) ? m : (m - H);
  K2 r = ctf(ka, kb, p, p + H);
  return (m < H) ? r.a : r.b;
#endif
}

__device__ __forceinline__ float bits_to_uniform(uint32_t bits) {
  // jax: bitcast(bits >> 9 | 0x3f800000) - 1.0
  return __uint_as_float((bits >> 9) | 0x3f800000u) - 1.0f;
}

__global__ void prep_kernel(const float* __restrict__ gamma,
                            float* __restrict__ jsym,
                            float* __restrict__ betas) {
  int e = blockIdx.x * blockDim.x + threadIdx.x;   // 0..65535
  int i = e / kN, j = e % kN;
  float v = 0.0f;
  if (i < j) v = gamma[i * kN + j];
  else if (i > j) v = gamma[j * kN + i];
  jsym[e] = v;
  if (e < kSweeps) {
    double l0 = log(0.1), l1 = log(5.0);
    betas[e] = (float)exp(l0 + (l1 - l0) * (double)e / (double)(kSweeps - 1));
  }
}

// One VALU op per element: f32 fma with the f16 spin operand converted in-op.
// Conversion of +-1.0h to f32 is exact, then fp32 fma -> bit-identical to
// fmaf(+-1.0f, J, acc). op_sel picks lo/hi half of the packed u32.
#define FMIX_LO(a, w, j)                                                      \
  asm("v_fma_mix_f32 %0, %1, %2, %0 op_sel:[0,0,0] op_sel_hi:[1,0,0]"         \
      : "+v"(a) : "v"(w), "v"(j))
#define FMIX_HI(a, w, j)                                                      \
  asm("v_fma_mix_f32 %0, %1, %2, %0 op_sel:[1,0,0] op_sel_hi:[1,0,0]"         \
      : "+v"(a) : "v"(w), "v"(j))

// Exact matvec: acc[g] += sum_j s[g][j] * Jrow[j], j ascending, fp32 chain.
// Spins are fp16 (+-1.0h) in LDS: one ds_read_b128 = 8 spins.
// Software-pipelined A/B (chunk = 8 j's, 32 chunks), no register copies.
__device__ __forceinline__ void matvec_h(const unsigned short* __restrict__ sh,
                                         const float4* __restrict__ jrow4,
                                         float (&acc)[kSamp]) {
#define LDSP(g, c) (*(const uint4*)(sh + (g) * kN + (c) * 8))
#define CONSUME(SP, J0, J1)                                                   \
  _Pragma("unroll")                                                           \
  for (int g = 0; g < kSamp; ++g) {                                           \
    FMIX_LO(acc[g], SP[g].x, J0.x); FMIX_HI(acc[g], SP[g].x, J0.y);           \
    FMIX_LO(acc[g], SP[g].y, J0.z); FMIX_HI(acc[g], SP[g].y, J0.w);           \
    FMIX_LO(acc[g], SP[g].z, J1.x); FMIX_HI(acc[g], SP[g].z, J1.y);           \
    FMIX_LO(acc[g], SP[g].w, J1.z); FMIX_HI(acc[g], SP[g].w, J1.w);           \
  }

  uint4 A[kSamp], B[kSamp];
  float4 jA0, jA1, jB0, jB1;
#pragma unroll
  for (int g = 0; g < kSamp; ++g) A[g] = LDSP(g, 0);
  jA0 = jrow4[0]; jA1 = jrow4[1];

#pragma unroll 1
  for (int k = 0; k < 15; ++k) {
    const int c = 2 * k;
    // body 1: prefetch chunk c+1 -> B, consume chunk c (A)
#pragma unroll
    for (int g = 0; g < kSamp; ++g) B[g] = LDSP(g, c + 1);
    jB0 = jrow4[2 * c + 2]; jB1 = jrow4[2 * c + 3];
    CONSUME(A, jA0, jA1)
    // body 2: prefetch chunk c+2 -> A, consume chunk c+1 (B)
#pragma unroll
    for (int g = 0; g < kSamp; ++g) A[g] = LDSP(g, c + 2);
    jA0 = jrow4[2 * c + 4]; jA1 = jrow4[2 * c + 5];
    CONSUME(B, jB0, jB1)
  }
  // tail: consume chunk 30 (A) while prefetching 31 -> B, then consume 31
#pragma unroll
  for (int g = 0; g < kSamp; ++g) B[g] = LDSP(g, 31);
  jB0 = jrow4[62]; jB1 = jrow4[63];
  CONSUME(A, jA0, jA1)
  CONSUME(B, jB0, jB1)
#undef LDSP
#undef CONSUME
}

__global__ __launch_bounds__(256) void anneal_kernel(
    const float* __restrict__ thetas, const float* __restrict__ jsym,
    const float* __restrict__ betas, float* __restrict__ out) {
  // fp16 spins (+1.0h=0x3C00, -1.0h=0xBC00), double-buffered: 8 KiB total
  __shared__ __align__(16) unsigned short sh_h[2][kSamp][kN];
  __shared__ float sh_red[kSamp][4];

  const int i = threadIdx.x;           // spin index (row of Jsym)
  const int b0 = blockIdx.x * kSamp;   // first sample of this block
  const int lane = i & 63;
  const int wid = i >> 6;

  float th[kSamp], sreg[kSamp];
#pragma unroll
  for (int g = 0; g < kSamp; ++g) th[g] = thetas[(b0 + g) * kN + i];

  // s0 = where(bernoulli(k0, 0.5), 1, -1) ; bernoulli = uniform < 0.5
#pragma unroll
  for (int g = 0; g < kSamp; ++g) {
    uint32_t m = (uint32_t)((b0 + g) * kN + i);
    float u = bits_to_uniform(rng_bits32(g_keys.s0k[0], g_keys.s0k[1], m));
    sreg[g] = (u < 0.5f) ? 1.0f : -1.0f;
    sh_h[0][g][i] = (sreg[g] < 0.0f) ? (unsigned short)0xBC00
                                     : (unsigned short)0x3C00;
  }
  __syncthreads();

  // row i of Jsym; by symmetry local_i = sum_j Jsym[i][j] * s[j]
  const float4* __restrict__ jrow4 = (const float4*)(jsym + i * kN);
  int cur = 0;

#pragma unroll 1
  for (int t = 0; t < kSweeps; ++t) {
    const float beta = betas[t];       // issued early, consumed after matvec

    float acc[kSamp];
#pragma unroll
    for (int g = 0; g < kSamp; ++g) acc[g] = 0.0f;

    matvec_h(&sh_h[cur][0][0], jrow4, acc);

    const int nxt = cur ^ 1;
    const uint32_t k1a = g_keys.sk[t][0], k1b = g_keys.sk[t][1];
    const uint32_t k2a = g_keys.sk[t][2], k2b = g_keys.sk[t][3];
#pragma unroll
    for (int g = 0; g < kSamp; ++g) {
      float s = sreg[g];
      float local = th[g] + acc[g];
      float dE = -2.0f * s * local;          // exact: (-2*s) is a power of two
      float pr = expf(-beta * dE);
      uint32_t m = (uint32_t)((b0 + g) * kN + i);
      uint32_t b1 = rng_bits32(k1a, k1b, m);
      uint32_t b2 = rng_bits32(k2a, k2b, m);
      float u1 = bits_to_uniform(b1);
      // u2 < 0.5  <=>  bit31(b2) == 0  (bit-exact)
      if ((u1 < pr) && ((b2 >> 31) == 0u)) s = -s;
      sreg[g] = s;
      sh_h[nxt][g][i] = (s < 0.0f) ? (unsigned short)0xBC00
                                   : (unsigned short)0x3C00;
    }
    __syncthreads();   // nxt-buffer writes visible before next sweep reads
    cur = nxt;
  }

  // E_b = sum_i s_i*theta_i + 0.5 * sum_i s_i * (Jsym s)_i
  {
    float acc[kSamp];
#pragma unroll
    for (int g = 0; g < kSamp; ++g) acc[g] = 0.0f;
    matvec_h(&sh_h[cur][0][0], jrow4, acc);

#pragma unroll
    for (int g = 0; g < kSamp; ++g) {
      float v = sreg[g] * th[g] + 0.5f * (sreg[g] * acc[g]);
#pragma unroll
      for (int off = 32; off > 0; off >>= 1) v += __shfl_down(v, off);
      if (lane == 0) sh_red[g][wid] = v;
    }
    __syncthreads();
    if (threadIdx.x < kSamp) {
      int g = threadIdx.x;
      out[b0 + g] = sh_red[g][0] + sh_red[g][1] + sh_red[g][2] + sh_red[g][3];
    }
  }
}

}  // namespace

extern "C" void kernel_launch(void* const* d_in, const int* in_sizes, int n_in,
                              void* d_out, int out_size, void* d_ws, size_t ws_size,
                              hipStream_t stream) {
  const float* thetas = (const float*)d_in[0];   // [4096, 256]
  const float* gamma  = (const float*)d_in[1];   // [256, 256]
  float* jsym  = (float*)d_ws;                              // 256 KiB
  float* betas = (float*)((char*)d_ws + kN * kN * sizeof(float));

  hipLaunchKernelGGL(prep_kernel, dim3(kN), dim3(kN), 0, stream, gamma, jsym, betas);
  hipLaunchKernelGGL(anneal_kernel, dim3(kBlocks), dim3(256), 0, stream,
                     thetas, jsym, betas, (float*)d_out);
}